// Round 1
// baseline (665.284 us; speedup 1.0000x reference)
//
#include <hip/hip_runtime.h>
#include <hip/hip_bf16.h>
#include <math.h>

// ---------------------------------------------------------------------------
// 2-layer GAT on MI355X.
// Layer 1: in=128, H=8, C=32 (concat -> 256), +bias1, ELU
// Layer 2: in=256, H=1, C=64 (mean over 1 head = identity), +bias2
// Graph: E=800000 random edges + N=50000 self loops appended.
// Strategy: fp32 GEMMs (no fp32 MFMA on CDNA4 -> vector ALU), CSR built per
// call (histogram + single-block scan + scatter), per-dst-node aggregation
// blocks (atomic-free accumulate, coalesced h[src] row gathers).
// ---------------------------------------------------------------------------

#define LEAKY(e) ((e) > 0.f ? (e) : 0.2f * (e))

// ---------------- GEMM1: h1[N,256] = x[N,128] @ W1[128,256] ----------------
__global__ __launch_bounds__(256) void gemm1_kernel(
    const float* __restrict__ x, const float* __restrict__ W,
    float* __restrict__ h1, int n) {
  __shared__ float xs[16 * 128];
  int t = threadIdx.x;
  int row0 = blockIdx.x * 16;
  for (int idx = t; idx < 16 * 128; idx += 256) {
    int r = row0 + (idx >> 7);
    xs[idx] = (r < n) ? x[row0 * 128 + idx] : 0.f;
  }
  __syncthreads();
  float acc[16];
#pragma unroll
  for (int r = 0; r < 16; r++) acc[r] = 0.f;
  for (int k = 0; k < 128; k++) {
    float w = W[k * 256 + t];
#pragma unroll
    for (int r = 0; r < 16; r++) acc[r] = fmaf(xs[r * 128 + k], w, acc[r]);
  }
#pragma unroll
  for (int r = 0; r < 16; r++) {
    int rg = row0 + r;
    if (rg < n) h1[rg * 256 + t] = acc[r];
  }
}

// ------------- GEMM2: h2[N,64] = h_act[N,256] @ W2[256,64] -----------------
__global__ __launch_bounds__(256) void gemm2_kernel(
    const float* __restrict__ A, const float* __restrict__ W,
    float* __restrict__ h2, int n) {
  __shared__ float xs[32 * 256];  // 32 KB
  int t = threadIdx.x;
  int row0 = blockIdx.x * 32;
  int c = t & 63, g = t >> 6;
  for (int idx = t; idx < 32 * 256; idx += 256) {
    int r = row0 + (idx >> 8);
    xs[idx] = (r < n) ? A[row0 * 256 + idx] : 0.f;
  }
  __syncthreads();
  float acc[8];
#pragma unroll
  for (int r = 0; r < 8; r++) acc[r] = 0.f;
  for (int k = 0; k < 256; k++) {
    float wv = W[k * 64 + c];
#pragma unroll
    for (int r = 0; r < 8; r++) acc[r] = fmaf(xs[(g * 8 + r) * 256 + k], wv, acc[r]);
  }
#pragma unroll
  for (int r = 0; r < 8; r++) {
    int rg = row0 + g * 8 + r;
    if (rg < n) h2[rg * 64 + c] = acc[r];
  }
}

// --------- attention coefficients layer 1: a_src/a_dst [N,8] ---------------
__global__ __launch_bounds__(256) void att1_kernel(
    const float* __restrict__ h1, const float* __restrict__ att_src,
    const float* __restrict__ att_dst, float* __restrict__ a_src,
    float* __restrict__ a_dst, int n) {
  int idx = blockIdx.x * 256 + threadIdx.x;
  if (idx >= n * 8) return;
  int h = idx & 7;
  const float4* hp = (const float4*)(h1 + (size_t)idx * 32);
  const float4* asp = (const float4*)(att_src + h * 32);
  const float4* adp = (const float4*)(att_dst + h * 32);
  float s = 0.f, d = 0.f;
#pragma unroll
  for (int q = 0; q < 8; q++) {
    float4 v = hp[q], a = asp[q], b = adp[q];
    s += v.x * a.x + v.y * a.y + v.z * a.z + v.w * a.w;
    d += v.x * b.x + v.y * b.y + v.z * b.z + v.w * b.w;
  }
  a_src[idx] = s;
  a_dst[idx] = d;
}

// --------- attention coefficients layer 2: a_src/a_dst [N] -----------------
__global__ __launch_bounds__(256) void att2_kernel(
    const float* __restrict__ h2, const float* __restrict__ att_src,
    const float* __restrict__ att_dst, float* __restrict__ a_src,
    float* __restrict__ a_dst, int n) {
  int idx = blockIdx.x * 256 + threadIdx.x;
  if (idx >= n) return;
  const float4* hp = (const float4*)(h2 + (size_t)idx * 64);
  float s = 0.f, d = 0.f;
#pragma unroll
  for (int q = 0; q < 16; q++) {
    float4 v = hp[q];
    float4 a = ((const float4*)att_src)[q];
    float4 b = ((const float4*)att_dst)[q];
    s += v.x * a.x + v.y * a.y + v.z * a.z + v.w * a.w;
    d += v.x * b.x + v.y * b.y + v.z * b.z + v.w * b.w;
  }
  a_src[idx] = s;
  a_dst[idx] = d;
}

// ------------------------- CSR construction --------------------------------
__global__ __launch_bounds__(256) void hist_kernel(
    const int* __restrict__ ei, int E, int n, int* __restrict__ deg) {
  int idx = blockIdx.x * 256 + threadIdx.x;
  if (idx >= E + n) return;
  int d = (idx < E) ? ei[E + idx] : (idx - E);
  atomicAdd(&deg[d], 1);
}

__global__ __launch_bounds__(1024) void scan_kernel(
    const int* __restrict__ deg, int* __restrict__ rowptr, int n) {
  __shared__ int sbuf[1024];
  __shared__ int stot;
  int t = threadIdx.x;
  int carry = 0;
  for (int base = 0; base < n; base += 1024) {
    int i = base + t;
    int v = (i < n) ? deg[i] : 0;
    sbuf[t] = v;
    __syncthreads();
    int x = v;
    for (int off = 1; off < 1024; off <<= 1) {
      int y = (t >= off) ? sbuf[t - off] : 0;
      __syncthreads();
      x += y;
      sbuf[t] = x;
      __syncthreads();
    }
    if (i < n) rowptr[i] = carry + x - v;  // exclusive scan
    if (t == 1023) stot = x;
    __syncthreads();
    carry += stot;
    __syncthreads();
  }
  if (t == 0) rowptr[n] = carry;
}

__global__ __launch_bounds__(256) void cursor_kernel(
    const int* __restrict__ rowptr, int* __restrict__ cursor, int n) {
  int idx = blockIdx.x * 256 + threadIdx.x;
  if (idx < n) cursor[idx] = rowptr[idx];
}

__global__ __launch_bounds__(256) void scatter_kernel(
    const int* __restrict__ ei, int E, int n, int* __restrict__ cursor,
    int* __restrict__ csr_src) {
  int idx = blockIdx.x * 256 + threadIdx.x;
  if (idx >= E + n) return;
  int s, d;
  if (idx < E) {
    s = ei[idx];
    d = ei[E + idx];
  } else {
    s = d = idx - E;
  }
  int pos = atomicAdd(&cursor[d], 1);
  csr_src[pos] = s;
}

// ------- layer-1 aggregation: softmax over in-edges + msg sum + bias+ELU ---
// one 256-thread block per dst node; thread t owns channel t (head t>>5)
__global__ __launch_bounds__(256) void agg1_kernel(
    const int* __restrict__ rowptr, const int* __restrict__ csr_src,
    const float* __restrict__ a_src, const float* __restrict__ a_dst,
    const float* __restrict__ h1, const float* __restrict__ bias,
    float* __restrict__ h_act) {
  int d = blockIdx.x;
  int t = threadIdx.x;
  int hh = t >> 5;  // head of this channel
  int j = t & 31;
  __shared__ float m_s[8], rinv_s[8], adst_s[8];
  __shared__ int sbuf[64];
  __shared__ float ab[64 * 8];
  int base = rowptr[d];
  int cnt = rowptr[d + 1] - base;
  if (t < 8) adst_s[t] = a_dst[d * 8 + t];
  __syncthreads();
  float adst = adst_s[hh];
  // max over edges (32 lanes per head)
  float mx = -3.0e38f;
  for (int i = j; i < cnt; i += 32) {
    int s = csr_src[base + i];
    float e = a_src[s * 8 + hh] + adst;
    e = LEAKY(e);
    mx = fmaxf(mx, e);
  }
#pragma unroll
  for (int o = 16; o; o >>= 1) mx = fmaxf(mx, __shfl_xor(mx, o, 32));
  // sum of exp(e - max)
  float sm = 0.f;
  for (int i = j; i < cnt; i += 32) {
    int s = csr_src[base + i];
    float e = a_src[s * 8 + hh] + adst;
    e = LEAKY(e);
    sm += __expf(e - mx);
  }
#pragma unroll
  for (int o = 16; o; o >>= 1) sm += __shfl_xor(sm, o, 32);
  if (j == 0) {
    m_s[hh] = mx;
    rinv_s[hh] = 1.f / (sm + 1e-16f);
  }
  __syncthreads();
  // chunked: stage alpha per (edge, head) in LDS, then channel-parallel fma
  float acc = 0.f;
  for (int cs = 0; cs < cnt; cs += 64) {
    int nc = min(64, cnt - cs);
    if (t < nc) sbuf[t] = csr_src[base + cs + t];
    __syncthreads();
    for (int idx = t; idx < nc * 8; idx += 256) {
      int el = idx >> 3, h2 = idx & 7;
      int s = sbuf[el];
      float e = a_src[s * 8 + h2] + adst_s[h2];
      e = LEAKY(e);
      ab[idx] = __expf(e - m_s[h2]) * rinv_s[h2];
    }
    __syncthreads();
    for (int el = 0; el < nc; el++) {
      acc = fmaf(h1[(size_t)sbuf[el] * 256 + t], ab[el * 8 + hh], acc);
    }
    __syncthreads();
  }
  float v = acc + bias[t];
  h_act[(size_t)d * 256 + t] = v > 0.f ? v : expm1f(v);
}

// ------- layer-2 aggregation: H=1, C=64; one wave per dst node -------------
__global__ __launch_bounds__(256) void agg2_kernel(
    const int* __restrict__ rowptr, const int* __restrict__ csr_src,
    const float* __restrict__ a_src, const float* __restrict__ a_dst,
    const float* __restrict__ h2, const float* __restrict__ bias,
    float* __restrict__ out, int n) {
  int w = threadIdx.x >> 6;
  int lane = threadIdx.x & 63;
  int d = blockIdx.x * 4 + w;
  if (d >= n) return;
  int base = rowptr[d];
  int cnt = rowptr[d + 1] - base;
  float adst = a_dst[d];
  float mx = -3.0e38f;
  for (int i = lane; i < cnt; i += 64) {
    int s = csr_src[base + i];
    float e = a_src[s] + adst;
    e = LEAKY(e);
    mx = fmaxf(mx, e);
  }
#pragma unroll
  for (int o = 32; o; o >>= 1) mx = fmaxf(mx, __shfl_xor(mx, o, 64));
  float sm = 0.f;
  for (int i = lane; i < cnt; i += 64) {
    int s = csr_src[base + i];
    float e = a_src[s] + adst;
    e = LEAKY(e);
    sm += __expf(e - mx);
  }
#pragma unroll
  for (int o = 32; o; o >>= 1) sm += __shfl_xor(sm, o, 64);
  float rinv = 1.f / (sm + 1e-16f);
  float acc = 0.f;
  for (int i = 0; i < cnt; i++) {
    int s = csr_src[base + i];
    float e = a_src[s] + adst;
    e = LEAKY(e);
    float al = __expf(e - mx) * rinv;
    acc = fmaf(h2[(size_t)s * 64 + lane], al, acc);
  }
  out[(size_t)d * 64 + lane] = acc + bias[lane];
}

// ---------------------------------------------------------------------------
extern "C" void kernel_launch(void* const* d_in, const int* in_sizes, int n_in,
                              void* d_out, int out_size, void* d_ws, size_t ws_size,
                              hipStream_t stream) {
  const float* x        = (const float*)d_in[0];
  const int*   ei       = (const int*)d_in[1];
  const float* W1       = (const float*)d_in[3];
  const float* att_src1 = (const float*)d_in[4];
  const float* att_dst1 = (const float*)d_in[5];
  const float* bias1    = (const float*)d_in[6];
  const float* W2       = (const float*)d_in[7];
  const float* att_src2 = (const float*)d_in[8];
  const float* att_dst2 = (const float*)d_in[9];
  const float* bias2    = (const float*)d_in[10];
  float* out = (float*)d_out;

  int N = in_sizes[0] / 128;
  int E = in_sizes[1] / 2;
  int Etot = E + N;

  // workspace carve-out
  char* ws = (char*)d_ws;
  size_t off = 0;
  auto carve = [&](size_t bytes) -> void* {
    void* p = ws + off;
    off += (bytes + 255) & ~(size_t)255;
    return p;
  };
  float* h1     = (float*)carve((size_t)N * 256 * 4);
  float* h_act  = (float*)carve((size_t)N * 256 * 4);
  float* h2     = (float*)carve((size_t)N * 64 * 4);
  float* a_src1 = (float*)carve((size_t)N * 8 * 4);
  float* a_dst1 = (float*)carve((size_t)N * 8 * 4);
  float* a_src2 = (float*)carve((size_t)N * 4);
  float* a_dst2 = (float*)carve((size_t)N * 4);
  int* rowptr   = (int*)carve((size_t)(N + 1) * 4);
  int* cursor   = (int*)carve((size_t)N * 4);
  int* deg      = (int*)carve((size_t)N * 4);
  int* csr_src  = (int*)carve((size_t)Etot * 4);
  (void)ws_size; (void)n_in; (void)out_size;

  // layer 1 projection + attention coefficients
  gemm1_kernel<<<(N + 15) / 16, 256, 0, stream>>>(x, W1, h1, N);
  att1_kernel<<<(N * 8 + 255) / 256, 256, 0, stream>>>(h1, att_src1, att_dst1,
                                                       a_src1, a_dst1, N);
  // CSR build (shared by both layers)
  hipMemsetAsync(deg, 0, (size_t)N * 4, stream);
  hist_kernel<<<(Etot + 255) / 256, 256, 0, stream>>>(ei, E, N, deg);
  scan_kernel<<<1, 1024, 0, stream>>>(deg, rowptr, N);
  cursor_kernel<<<(N + 255) / 256, 256, 0, stream>>>(rowptr, cursor, N);
  scatter_kernel<<<(Etot + 255) / 256, 256, 0, stream>>>(ei, E, N, cursor, csr_src);

  // layer 1 aggregation (+bias+ELU)
  agg1_kernel<<<N, 256, 0, stream>>>(rowptr, csr_src, a_src1, a_dst1, h1,
                                     bias1, h_act);
  // layer 2
  gemm2_kernel<<<(N + 31) / 32, 256, 0, stream>>>(h_act, W2, h2, N);
  att2_kernel<<<(N + 255) / 256, 256, 0, stream>>>(h2, att_src2, att_dst2,
                                                   a_src2, a_dst2, N);
  agg2_kernel<<<(N + 3) / 4, 256, 0, stream>>>(rowptr, csr_src, a_src2,
                                               a_dst2, h2, bias2, out, N);
}

// Round 2
// 485.773 us; speedup vs baseline: 1.3695x; 1.3695x over previous
//
#include <hip/hip_runtime.h>
#include <hip/hip_bf16.h>
#include <math.h>

// ---------------------------------------------------------------------------
// 2-layer GAT on MI355X (gfx950).
// L1: in=128, H=8, C=32 (concat->256) +bias1, ELU.  L2: in=256, H=1, C=64 +bias2.
// E=800000 random edges + N=50000 self loops.
// R2 changes: register-tiled fp32 GEMMs (4x4/thread), hierarchical scan,
// precomputed exp(leaky(e)) per (edge,head) in CSR order (no max-subtraction:
// e in +-~10, exp() fp32-safe, softmax value identical), 8-deep batched
// gathers in both aggregation kernels to break the load-latency chain.
// ---------------------------------------------------------------------------

#define LEAKY(e) ((e) > 0.f ? (e) : 0.2f * (e))

// ------------- tiled GEMM: C[n,NTOT] = A[n,K] @ B[K,NTOT] ------------------
// 64x64 tile per 256-thread block, KC=64, 4x4 register tile per thread.
template <int K, int NTOT>
__global__ __launch_bounds__(256) void gemm_tile_kernel(
    const float* __restrict__ A, const float* __restrict__ B,
    float* __restrict__ C, int n) {
  const int KC = 64;
  __shared__ float As[KC][68];  // [k][m], pad 68 keeps 16B align + spreads banks
  __shared__ float Bs[KC][68];  // [k][c]
  int t = threadIdx.x;
  int tx = t & 15, ty = t >> 4;
  int m0 = blockIdx.x * 64;
  int c0 = blockIdx.y * 64;
  float acc[4][4] = {};
  for (int kc = 0; kc < K; kc += KC) {
#pragma unroll
    for (int rep = 0; rep < 4; rep++) {
      int lin = rep * 256 + t;  // 0..1023
      int r = lin >> 4;         // 0..63
      int k4 = (lin & 15) * 4;  // 0..60
      int gr = m0 + r;
      float4 v = (gr < n) ? *(const float4*)(A + (size_t)gr * K + kc + k4)
                          : make_float4(0.f, 0.f, 0.f, 0.f);
      As[k4 + 0][r] = v.x;
      As[k4 + 1][r] = v.y;
      As[k4 + 2][r] = v.z;
      As[k4 + 3][r] = v.w;
    }
#pragma unroll
    for (int rep = 0; rep < 4; rep++) {
      int lin = rep * 256 + t;
      int r = lin >> 4;         // k in chunk
      int c4 = (lin & 15) * 4;
      float4 v = *(const float4*)(B + (size_t)(kc + r) * NTOT + c0 + c4);
      *(float4*)&Bs[r][c4] = v;
    }
    __syncthreads();
    for (int k = 0; k < KC; k++) {
      float4 a4 = *(const float4*)&As[k][ty * 4];
      float4 b4 = *(const float4*)&Bs[k][tx * 4];
      float av[4] = {a4.x, a4.y, a4.z, a4.w};
      float bv[4] = {b4.x, b4.y, b4.z, b4.w};
#pragma unroll
      for (int i = 0; i < 4; i++)
#pragma unroll
        for (int j = 0; j < 4; j++) acc[i][j] = fmaf(av[i], bv[j], acc[i][j]);
    }
    __syncthreads();
  }
#pragma unroll
  for (int i = 0; i < 4; i++) {
    int gr = m0 + ty * 4 + i;
    if (gr < n)
      *(float4*)(C + (size_t)gr * NTOT + c0 + tx * 4) =
          make_float4(acc[i][0], acc[i][1], acc[i][2], acc[i][3]);
  }
}

// --------- attention coefficients layer 1: a_src/a_dst [N,8] ---------------
__global__ __launch_bounds__(256) void att1_kernel(
    const float* __restrict__ h1, const float* __restrict__ att_src,
    const float* __restrict__ att_dst, float* __restrict__ a_src,
    float* __restrict__ a_dst, int n) {
  int idx = blockIdx.x * 256 + threadIdx.x;
  if (idx >= n * 8) return;
  int h = idx & 7;
  const float4* hp = (const float4*)(h1 + (size_t)idx * 32);
  const float4* asp = (const float4*)(att_src + h * 32);
  const float4* adp = (const float4*)(att_dst + h * 32);
  float s = 0.f, d = 0.f;
#pragma unroll
  for (int q = 0; q < 8; q++) {
    float4 v = hp[q], a = asp[q], b = adp[q];
    s += v.x * a.x + v.y * a.y + v.z * a.z + v.w * a.w;
    d += v.x * b.x + v.y * b.y + v.z * b.z + v.w * b.w;
  }
  a_src[idx] = s;
  a_dst[idx] = d;
}

// --------- attention coefficients layer 2: a_src/a_dst [N] -----------------
__global__ __launch_bounds__(256) void att2_kernel(
    const float* __restrict__ h2, const float* __restrict__ att_src,
    const float* __restrict__ att_dst, float* __restrict__ a_src,
    float* __restrict__ a_dst, int n) {
  int idx = blockIdx.x * 256 + threadIdx.x;
  if (idx >= n) return;
  const float4* hp = (const float4*)(h2 + (size_t)idx * 64);
  float s = 0.f, d = 0.f;
#pragma unroll
  for (int q = 0; q < 16; q++) {
    float4 v = hp[q];
    float4 a = ((const float4*)att_src)[q];
    float4 b = ((const float4*)att_dst)[q];
    s += v.x * a.x + v.y * a.y + v.z * a.z + v.w * a.w;
    d += v.x * b.x + v.y * b.y + v.z * b.z + v.w * b.w;
  }
  a_src[idx] = s;
  a_dst[idx] = d;
}

// ------------------------- CSR construction --------------------------------
__global__ __launch_bounds__(256) void hist_kernel(
    const int* __restrict__ ei, int E, int n, int* __restrict__ deg) {
  int idx = blockIdx.x * 256 + threadIdx.x;
  if (idx >= E + n) return;
  int d = (idx < E) ? ei[E + idx] : (idx - E);
  atomicAdd(&deg[d], 1);
}

// hierarchical exclusive scan of deg -> rowptr (+cursor init)
__global__ __launch_bounds__(256) void scan1_kernel(
    const int* __restrict__ deg, int* __restrict__ bsum, int n) {
  __shared__ int ws[4];
  int t = threadIdx.x;
  int i = blockIdx.x * 256 + t;
  int v = (i < n) ? deg[i] : 0;
  int wv = v;
#pragma unroll
  for (int o = 32; o; o >>= 1) wv += __shfl_xor(wv, o, 64);
  if ((t & 63) == 0) ws[t >> 6] = wv;
  __syncthreads();
  if (t == 0) bsum[blockIdx.x] = ws[0] + ws[1] + ws[2] + ws[3];
}

__global__ __launch_bounds__(1024) void scan2_kernel(int* __restrict__ bsum,
                                                     int nb) {
  __shared__ int sb[1024];
  int t = threadIdx.x;
  int v = (t < nb) ? bsum[t] : 0;
  sb[t] = v;
  __syncthreads();
  int x = v;
  for (int off = 1; off < 1024; off <<= 1) {
    int y = (t >= off) ? sb[t - off] : 0;
    __syncthreads();
    x += y;
    sb[t] = x;
    __syncthreads();
  }
  if (t < nb) bsum[t] = x - v;  // exclusive
}

__global__ __launch_bounds__(256) void scan3_kernel(
    const int* __restrict__ deg, const int* __restrict__ bsum,
    int* __restrict__ rowptr, int* __restrict__ cursor, int n) {
  __shared__ int sb[256];
  int t = threadIdx.x;
  int i = blockIdx.x * 256 + t;
  int v = (i < n) ? deg[i] : 0;
  sb[t] = v;
  __syncthreads();
  int x = v;
  for (int off = 1; off < 256; off <<= 1) {
    int y = (t >= off) ? sb[t - off] : 0;
    __syncthreads();
    x += y;
    sb[t] = x;
    __syncthreads();
  }
  int excl = x - v + bsum[blockIdx.x];
  if (i < n) {
    rowptr[i] = excl;
    cursor[i] = excl;
  }
  if (i == n - 1) rowptr[n] = excl + v;
}

__global__ __launch_bounds__(256) void scatter_kernel(
    const int* __restrict__ ei, int E, int n, int* __restrict__ cursor,
    int* __restrict__ csr_src, int* __restrict__ csr_dst) {
  int idx = blockIdx.x * 256 + threadIdx.x;
  if (idx >= E + n) return;
  int s, d;
  if (idx < E) {
    s = ei[idx];
    d = ei[E + idx];
  } else {
    s = d = idx - E;
  }
  int pos = atomicAdd(&cursor[d], 1);
  csr_src[pos] = s;
  csr_dst[pos] = d;
}

// ----- per-(edge,head) exp(leaky(e)) in CSR order, layer 1 [Etot,8] --------
__global__ __launch_bounds__(256) void xs1_kernel(
    const int* __restrict__ csr_src, const int* __restrict__ csr_dst,
    const float* __restrict__ a_src, const float* __restrict__ a_dst,
    float* __restrict__ xs1, int Etot) {
  int idx = blockIdx.x * 256 + threadIdx.x;
  if (idx >= Etot * 8) return;
  int i = idx >> 3, h = idx & 7;
  int s = csr_src[i], d = csr_dst[i];
  float e = a_src[s * 8 + h] + a_dst[d * 8 + h];
  e = LEAKY(e);
  xs1[idx] = __expf(e);
}

// ----- per-edge exp(leaky(e)) in CSR order, layer 2 [Etot] -----------------
__global__ __launch_bounds__(256) void xs2_kernel(
    const int* __restrict__ csr_src, const int* __restrict__ csr_dst,
    const float* __restrict__ a_src, const float* __restrict__ a_dst,
    float* __restrict__ xs2, int Etot) {
  int i = blockIdx.x * 256 + threadIdx.x;
  if (i >= Etot) return;
  float e = a_src[csr_src[i]] + a_dst[csr_dst[i]];
  e = LEAKY(e);
  xs2[i] = __expf(e);
}

// ------- layer-1 aggregation: one 256-thr block per dst; thread owns ch t --
__global__ __launch_bounds__(256) void agg1_kernel(
    const int* __restrict__ rowptr, const int* __restrict__ csr_src,
    const float* __restrict__ xs1, const float* __restrict__ h1,
    const float* __restrict__ bias, float* __restrict__ h_act) {
  int d = blockIdx.x;
  int t = threadIdx.x;
  int hh = t >> 5;  // head of this output channel
  __shared__ float rinv_s[8];
  __shared__ float wsum[4][8];
  __shared__ float ab[32 * 8];
  int base = rowptr[d];
  int cnt = rowptr[d + 1] - base;
  // denominator per head: thread t covers entries t, t+256, ... (head = t&7)
  float p = 0.f;
  for (int i = t; i < cnt * 8; i += 256) p += xs1[base * 8 + i];
  p += __shfl_xor(p, 8, 64);
  p += __shfl_xor(p, 16, 64);
  p += __shfl_xor(p, 32, 64);
  if ((t & 63) < 8) wsum[t >> 6][t & 7] = p;
  __syncthreads();
  if (t < 8)
    rinv_s[t] = 1.f / (wsum[0][t] + wsum[1][t] + wsum[2][t] + wsum[3][t] + 1e-16f);
  __syncthreads();
  float rinv_h = rinv_s[t & 7];
  float acc = 0.f;
  for (int cs = 0; cs < cnt; cs += 32) {
    int nc = min(32, cnt - cs);
    if (t < nc * 8) ab[t] = xs1[base * 8 + cs * 8 + t] * rinv_h;  // [el][h]
    __syncthreads();
    int i = 0;
    for (; i + 8 <= nc; i += 8) {
      int s[8];
      float v[8], a[8];
#pragma unroll
      for (int j = 0; j < 8; j++) s[j] = csr_src[base + cs + i + j];
#pragma unroll
      for (int j = 0; j < 8; j++) v[j] = h1[(size_t)s[j] * 256 + t];
#pragma unroll
      for (int j = 0; j < 8; j++) a[j] = ab[(i + j) * 8 + hh];
#pragma unroll
      for (int j = 0; j < 8; j++) acc = fmaf(v[j], a[j], acc);
    }
    for (; i < nc; i++) {
      int s = csr_src[base + cs + i];
      acc = fmaf(h1[(size_t)s * 256 + t], ab[i * 8 + hh], acc);
    }
    __syncthreads();
  }
  float v = acc + bias[t];
  h_act[(size_t)d * 256 + t] = v > 0.f ? v : expm1f(v);
}

// ------- layer-2 aggregation: one wave per dst node ------------------------
__global__ __launch_bounds__(256) void agg2_kernel(
    const int* __restrict__ rowptr, const int* __restrict__ csr_src,
    const float* __restrict__ xs2, const float* __restrict__ h2,
    const float* __restrict__ bias, float* __restrict__ out, int n) {
  int w = threadIdx.x >> 6;
  int lane = threadIdx.x & 63;
  int d = blockIdx.x * 4 + w;
  if (d >= n) return;
  int base = rowptr[d];
  int cnt = rowptr[d + 1] - base;
  float p = 0.f;
  for (int i = lane; i < cnt; i += 64) p += xs2[base + i];
#pragma unroll
  for (int o = 32; o; o >>= 1) p += __shfl_xor(p, o, 64);
  float rinv = 1.f / (p + 1e-16f);
  float acc = 0.f;
  int i = 0;
  for (; i + 8 <= cnt; i += 8) {
    int s[8];
    float xv[8], v[8];
#pragma unroll
    for (int j = 0; j < 8; j++) s[j] = csr_src[base + i + j];
#pragma unroll
    for (int j = 0; j < 8; j++) xv[j] = xs2[base + i + j];
#pragma unroll
    for (int j = 0; j < 8; j++) v[j] = h2[(size_t)s[j] * 64 + lane];
#pragma unroll
    for (int j = 0; j < 8; j++) acc = fmaf(v[j], xv[j] * rinv, acc);
  }
  for (; i < cnt; i++) {
    int s = csr_src[base + i];
    acc = fmaf(h2[(size_t)s * 64 + lane], xs2[base + i] * rinv, acc);
  }
  out[(size_t)d * 64 + lane] = acc + bias[lane];
}

// ---------------------------------------------------------------------------
extern "C" void kernel_launch(void* const* d_in, const int* in_sizes, int n_in,
                              void* d_out, int out_size, void* d_ws, size_t ws_size,
                              hipStream_t stream) {
  const float* x        = (const float*)d_in[0];
  const int*   ei       = (const int*)d_in[1];
  const float* W1       = (const float*)d_in[3];
  const float* att_src1 = (const float*)d_in[4];
  const float* att_dst1 = (const float*)d_in[5];
  const float* bias1    = (const float*)d_in[6];
  const float* W2       = (const float*)d_in[7];
  const float* att_src2 = (const float*)d_in[8];
  const float* att_dst2 = (const float*)d_in[9];
  const float* bias2    = (const float*)d_in[10];
  float* out = (float*)d_out;

  int N = in_sizes[0] / 128;
  int E = in_sizes[1] / 2;
  int Etot = E + N;
  int nb = (N + 255) / 256;  // scan blocks (196 <= 1024)

  char* ws = (char*)d_ws;
  size_t off = 0;
  auto carve = [&](size_t bytes) -> void* {
    void* p = ws + off;
    off += (bytes + 255) & ~(size_t)255;
    return p;
  };
  float* h1     = (float*)carve((size_t)N * 256 * 4);
  float* h_act  = (float*)carve((size_t)N * 256 * 4);
  float* h2     = (float*)carve((size_t)N * 64 * 4);
  float* a_src1 = (float*)carve((size_t)N * 8 * 4);
  float* a_dst1 = (float*)carve((size_t)N * 8 * 4);
  float* a_src2 = (float*)carve((size_t)N * 4);
  float* a_dst2 = (float*)carve((size_t)N * 4);
  int* rowptr   = (int*)carve((size_t)(N + 1) * 4);
  int* cursor   = (int*)carve((size_t)N * 4);
  int* deg      = (int*)carve((size_t)N * 4);
  int* bsum     = (int*)carve((size_t)nb * 4);
  int* csr_src  = (int*)carve((size_t)Etot * 4);
  int* csr_dst  = (int*)carve((size_t)Etot * 4);
  float* xs1    = (float*)carve((size_t)Etot * 8 * 4);
  float* xs2    = (float*)carve((size_t)Etot * 4);
  (void)ws_size; (void)n_in; (void)out_size;

  // layer-1 projection + attention coefficients
  {
    dim3 g((N + 63) / 64, 4);
    gemm_tile_kernel<128, 256><<<g, 256, 0, stream>>>(x, W1, h1, N);
  }
  att1_kernel<<<(N * 8 + 255) / 256, 256, 0, stream>>>(h1, att_src1, att_dst1,
                                                       a_src1, a_dst1, N);
  // CSR build
  hipMemsetAsync(deg, 0, (size_t)N * 4, stream);
  hist_kernel<<<(Etot + 255) / 256, 256, 0, stream>>>(ei, E, N, deg);
  scan1_kernel<<<nb, 256, 0, stream>>>(deg, bsum, N);
  scan2_kernel<<<1, 1024, 0, stream>>>(bsum, nb);
  scan3_kernel<<<nb, 256, 0, stream>>>(deg, bsum, rowptr, cursor, N);
  scatter_kernel<<<(Etot + 255) / 256, 256, 0, stream>>>(ei, E, N, cursor,
                                                         csr_src, csr_dst);
  // layer-1 softmax numerators + aggregation (+bias+ELU)
  xs1_kernel<<<(Etot * 8 + 255) / 256, 256, 0, stream>>>(csr_src, csr_dst,
                                                         a_src1, a_dst1, xs1, Etot);
  agg1_kernel<<<N, 256, 0, stream>>>(rowptr, csr_src, xs1, h1, bias1, h_act);
  // layer 2
  {
    dim3 g((N + 63) / 64, 1);
    gemm_tile_kernel<256, 64><<<g, 256, 0, stream>>>(h_act, W2, h2, N);
  }
  att2_kernel<<<(N + 255) / 256, 256, 0, stream>>>(h2, att_src2, att_dst2,
                                                   a_src2, a_dst2, N);
  xs2_kernel<<<(Etot + 255) / 256, 256, 0, stream>>>(csr_src, csr_dst,
                                                     a_src2, a_dst2, xs2, Etot);
  agg2_kernel<<<(N + 3) / 4, 256, 0, stream>>>(rowptr, csr_src, xs2, h2,
                                               bias2, out, N);
}

// Round 3
// 415.285 us; speedup vs baseline: 1.6020x; 1.1697x over previous
//
#include <hip/hip_runtime.h>
#include <hip/hip_bf16.h>
#include <hip/hip_fp16.h>
#include <math.h>

// ---------------------------------------------------------------------------
// 2-layer GAT on MI355X (gfx950).
// L1: in=128, H=8, C=32 (concat->256) +bias1, ELU.  L2: in=256, H=1, C=64 +bias2.
// R3: projections stored fp16 (halves gather bytes; error budget 1.5e-2 vs
// current 3.9e-3), wave-per-dst aggregation (no LDS/barriers, 8-deep batched
// gathers), 128x64-tile GEMMs with 8x4 register blocking.
// ---------------------------------------------------------------------------

#define LEAKY(e) ((e) > 0.f ? (e) : 0.2f * (e))

struct __align__(8) H4 { __half2 a, b; };  // 4 halves

// ------- tiled GEMM, fp32 in, fp16 out: Ch[n,NTOT] = A[n,K] @ B[K,NTOT] ----
// 128x64 tile / 256 threads, KC=64, 8x4 register tile per thread.
template <int K, int NTOT>
__global__ __launch_bounds__(256) void gemm_half_kernel(
    const float* __restrict__ A, const float* __restrict__ B,
    __half* __restrict__ Ch, int n) {
  const int KC = 64;
  __shared__ float As[KC][132];  // [k][m] transposed, pad 132
  __shared__ float Bs[KC][68];   // [k][c]
  int t = threadIdx.x;
  int tx = t & 15, ty = t >> 4;
  int m0 = blockIdx.x * 128;
  int c0 = blockIdx.y * 64;
  float acc[8][4] = {};
  for (int kc = 0; kc < K; kc += KC) {
    // A chunk: 128 rows x 64 k. r = lin&127 -> conflict-free transposed store.
#pragma unroll
    for (int rep = 0; rep < 8; rep++) {
      int lin = rep * 256 + t;  // 0..2047
      int r = lin & 127;
      int k4 = (lin >> 7) * 4;  // 0..60
      int gr = m0 + r;
      float4 v = (gr < n) ? *(const float4*)(A + (size_t)gr * K + kc + k4)
                          : make_float4(0.f, 0.f, 0.f, 0.f);
      As[k4 + 0][r] = v.x;
      As[k4 + 1][r] = v.y;
      As[k4 + 2][r] = v.z;
      As[k4 + 3][r] = v.w;
    }
    // B chunk: 64 k x 64 c, coalesced.
#pragma unroll
    for (int rep = 0; rep < 4; rep++) {
      int lin = rep * 256 + t;
      int r = lin >> 4;
      int c4 = (lin & 15) * 4;
      *(float4*)&Bs[r][c4] = *(const float4*)(B + (size_t)(kc + r) * NTOT + c0 + c4);
    }
    __syncthreads();
#pragma unroll 4
    for (int k = 0; k < KC; k++) {
      float4 a0 = *(const float4*)&As[k][ty * 8];
      float4 a1 = *(const float4*)&As[k][ty * 8 + 4];
      float4 b4 = *(const float4*)&Bs[k][tx * 4];
      float av[8] = {a0.x, a0.y, a0.z, a0.w, a1.x, a1.y, a1.z, a1.w};
      float bv[4] = {b4.x, b4.y, b4.z, b4.w};
#pragma unroll
      for (int i = 0; i < 8; i++)
#pragma unroll
        for (int j = 0; j < 4; j++) acc[i][j] = fmaf(av[i], bv[j], acc[i][j]);
    }
    __syncthreads();
  }
#pragma unroll
  for (int i = 0; i < 8; i++) {
    int gr = m0 + ty * 8 + i;
    if (gr < n) {
      H4 hv;
      hv.a = __floats2half2_rn(acc[i][0], acc[i][1]);
      hv.b = __floats2half2_rn(acc[i][2], acc[i][3]);
      *(H4*)(Ch + (size_t)gr * NTOT + c0 + tx * 4) = hv;
    }
  }
}

// --------- attention coefficients layer 1 (fp16 h): a_src/a_dst [N,8] ------
__global__ __launch_bounds__(256) void att1_kernel(
    const __half* __restrict__ h1h, const float* __restrict__ att_src,
    const float* __restrict__ att_dst, float* __restrict__ a_src,
    float* __restrict__ a_dst, int n) {
  int idx = blockIdx.x * 256 + threadIdx.x;
  if (idx >= n * 8) return;
  int h = idx & 7;
  const H4* hp = (const H4*)(h1h + (size_t)idx * 32);
  const float4* asp = (const float4*)(att_src + h * 32);
  const float4* adp = (const float4*)(att_dst + h * 32);
  float s = 0.f, d = 0.f;
#pragma unroll
  for (int q = 0; q < 8; q++) {
    H4 hv = hp[q];
    float2 p0 = __half22float2(hv.a), p1 = __half22float2(hv.b);
    float4 a = asp[q], b = adp[q];
    s += p0.x * a.x + p0.y * a.y + p1.x * a.z + p1.y * a.w;
    d += p0.x * b.x + p0.y * b.y + p1.x * b.z + p1.y * b.w;
  }
  a_src[idx] = s;
  a_dst[idx] = d;
}

// --------- attention coefficients layer 2 (fp16 h): a_src/a_dst [N] --------
__global__ __launch_bounds__(256) void att2_kernel(
    const __half* __restrict__ h2h, const float* __restrict__ att_src,
    const float* __restrict__ att_dst, float* __restrict__ a_src,
    float* __restrict__ a_dst, int n) {
  int idx = blockIdx.x * 256 + threadIdx.x;
  if (idx >= n) return;
  const H4* hp = (const H4*)(h2h + (size_t)idx * 64);
  float s = 0.f, d = 0.f;
#pragma unroll
  for (int q = 0; q < 16; q++) {
    H4 hv = hp[q];
    float2 p0 = __half22float2(hv.a), p1 = __half22float2(hv.b);
    float4 a = ((const float4*)att_src)[q];
    float4 b = ((const float4*)att_dst)[q];
    s += p0.x * a.x + p0.y * a.y + p1.x * a.z + p1.y * a.w;
    d += p0.x * b.x + p0.y * b.y + p1.x * b.z + p1.y * b.w;
  }
  a_src[idx] = s;
  a_dst[idx] = d;
}

// ------------------------- CSR construction --------------------------------
__global__ __launch_bounds__(256) void hist_kernel(
    const int* __restrict__ ei, int E, int n, int* __restrict__ deg) {
  int idx = blockIdx.x * 256 + threadIdx.x;
  if (idx >= E + n) return;
  int d = (idx < E) ? ei[E + idx] : (idx - E);
  atomicAdd(&deg[d], 1);
}

__global__ __launch_bounds__(256) void scan1_kernel(
    const int* __restrict__ deg, int* __restrict__ bsum, int n) {
  __shared__ int ws[4];
  int t = threadIdx.x;
  int i = blockIdx.x * 256 + t;
  int v = (i < n) ? deg[i] : 0;
  int wv = v;
#pragma unroll
  for (int o = 32; o; o >>= 1) wv += __shfl_xor(wv, o, 64);
  if ((t & 63) == 0) ws[t >> 6] = wv;
  __syncthreads();
  if (t == 0) bsum[blockIdx.x] = ws[0] + ws[1] + ws[2] + ws[3];
}

__global__ __launch_bounds__(1024) void scan2_kernel(int* __restrict__ bsum,
                                                     int nb) {
  __shared__ int sb[1024];
  int t = threadIdx.x;
  int v = (t < nb) ? bsum[t] : 0;
  sb[t] = v;
  __syncthreads();
  int x = v;
  for (int off = 1; off < 1024; off <<= 1) {
    int y = (t >= off) ? sb[t - off] : 0;
    __syncthreads();
    x += y;
    sb[t] = x;
    __syncthreads();
  }
  if (t < nb) bsum[t] = x - v;  // exclusive
}

__global__ __launch_bounds__(256) void scan3_kernel(
    const int* __restrict__ deg, const int* __restrict__ bsum,
    int* __restrict__ rowptr, int* __restrict__ cursor, int n) {
  __shared__ int sb[256];
  int t = threadIdx.x;
  int i = blockIdx.x * 256 + t;
  int v = (i < n) ? deg[i] : 0;
  sb[t] = v;
  __syncthreads();
  int x = v;
  for (int off = 1; off < 256; off <<= 1) {
    int y = (t >= off) ? sb[t - off] : 0;
    __syncthreads();
    x += y;
    sb[t] = x;
    __syncthreads();
  }
  int excl = x - v + bsum[blockIdx.x];
  if (i < n) {
    rowptr[i] = excl;
    cursor[i] = excl;
  }
  if (i == n - 1) rowptr[n] = excl + v;
}

__global__ __launch_bounds__(256) void scatter_kernel(
    const int* __restrict__ ei, int E, int n, int* __restrict__ cursor,
    int* __restrict__ csr_src, int* __restrict__ csr_dst) {
  int idx = blockIdx.x * 256 + threadIdx.x;
  if (idx >= E + n) return;
  int s, d;
  if (idx < E) {
    s = ei[idx];
    d = ei[E + idx];
  } else {
    s = d = idx - E;
  }
  int pos = atomicAdd(&cursor[d], 1);
  csr_src[pos] = s;
  csr_dst[pos] = d;
}

// ----- per-(edge,head) exp(leaky(e)) in CSR order, layer 1 [Etot,8] --------
__global__ __launch_bounds__(256) void xs1_kernel(
    const int* __restrict__ csr_src, const int* __restrict__ csr_dst,
    const float* __restrict__ a_src, const float* __restrict__ a_dst,
    float* __restrict__ xs1, int Etot) {
  int idx = blockIdx.x * 256 + threadIdx.x;
  if (idx >= Etot * 8) return;
  int i = idx >> 3, h = idx & 7;
  int s = csr_src[i], d = csr_dst[i];
  float e = a_src[s * 8 + h] + a_dst[d * 8 + h];
  e = LEAKY(e);
  xs1[idx] = __expf(e);
}

// ----- per-edge exp(leaky(e)) in CSR order, layer 2 [Etot] -----------------
__global__ __launch_bounds__(256) void xs2_kernel(
    const int* __restrict__ csr_src, const int* __restrict__ csr_dst,
    const float* __restrict__ a_src, const float* __restrict__ a_dst,
    float* __restrict__ xs2, int Etot) {
  int i = blockIdx.x * 256 + threadIdx.x;
  if (i >= Etot) return;
  float e = a_src[csr_src[i]] + a_dst[csr_dst[i]];
  e = LEAKY(e);
  xs2[i] = __expf(e);
}

// ------- layer-1 aggregation: one wave per dst; lane owns 4 channels -------
__global__ __launch_bounds__(256) void agg1_kernel(
    const int* __restrict__ rowptr, const int* __restrict__ csr_src,
    const float* __restrict__ xs1, const __half* __restrict__ h1h,
    const float* __restrict__ bias, float* __restrict__ h_act, int n) {
  int w = threadIdx.x >> 6, l = threadIdx.x & 63;
  int d = blockIdx.x * 4 + w;
  if (d >= n) return;
  int base = rowptr[d], cnt = rowptr[d + 1] - base;
  const float* xp = xs1 + (size_t)base * 8;
  // denominator per head: lane l covers head l&7 (stride 64 over [0,cnt*8))
  float p = 0.f;
  for (int i = l; i < cnt * 8; i += 64) p += xp[i];
  p += __shfl_xor(p, 8, 64);
  p += __shfl_xor(p, 16, 64);
  p += __shfl_xor(p, 32, 64);
  float rinv = 1.f / (p + 1e-16f);     // for head l&7
  int hh = l >> 3;                     // head of owned channels 4l..4l+3
  float rh = __shfl(rinv, hh, 64);     // rinv of head hh (lane hh holds it)
  float4 acc = make_float4(0.f, 0.f, 0.f, 0.f);
  int i = 0;
  for (; i + 8 <= cnt; i += 8) {
    int s[8];
    float xv[8];
    H4 v[8];
#pragma unroll
    for (int j = 0; j < 8; j++) s[j] = csr_src[base + i + j];
#pragma unroll
    for (int j = 0; j < 8; j++) xv[j] = xp[(i + j) * 8 + hh];
#pragma unroll
    for (int j = 0; j < 8; j++)
      v[j] = *(const H4*)(h1h + (size_t)s[j] * 256 + 4 * l);
#pragma unroll
    for (int j = 0; j < 8; j++) {
      float a = xv[j] * rh;
      float2 p0 = __half22float2(v[j].a), p1 = __half22float2(v[j].b);
      acc.x = fmaf(p0.x, a, acc.x);
      acc.y = fmaf(p0.y, a, acc.y);
      acc.z = fmaf(p1.x, a, acc.z);
      acc.w = fmaf(p1.y, a, acc.w);
    }
  }
  for (; i < cnt; i++) {
    int s = csr_src[base + i];
    float a = xp[i * 8 + hh] * rh;
    H4 v = *(const H4*)(h1h + (size_t)s * 256 + 4 * l);
    float2 p0 = __half22float2(v.a), p1 = __half22float2(v.b);
    acc.x = fmaf(p0.x, a, acc.x);
    acc.y = fmaf(p0.y, a, acc.y);
    acc.z = fmaf(p1.x, a, acc.z);
    acc.w = fmaf(p1.y, a, acc.w);
  }
  float4 b = *(const float4*)(bias + 4 * l);
  float4 o;
  o.x = acc.x + b.x;
  o.y = acc.y + b.y;
  o.z = acc.z + b.z;
  o.w = acc.w + b.w;
  o.x = o.x > 0.f ? o.x : expm1f(o.x);
  o.y = o.y > 0.f ? o.y : expm1f(o.y);
  o.z = o.z > 0.f ? o.z : expm1f(o.z);
  o.w = o.w > 0.f ? o.w : expm1f(o.w);
  *(float4*)(h_act + (size_t)d * 256 + 4 * l) = o;
}

// ------- layer-2 aggregation: wave per dst, 2 edge-slots x 32 ch-pairs -----
__global__ __launch_bounds__(256) void agg2_kernel(
    const int* __restrict__ rowptr, const int* __restrict__ csr_src,
    const float* __restrict__ xs2, const __half* __restrict__ h2h,
    const float* __restrict__ bias, float* __restrict__ out, int n) {
  int w = threadIdx.x >> 6, l = threadIdx.x & 63;
  int d = blockIdx.x * 4 + w;
  if (d >= n) return;
  int base = rowptr[d], cnt = rowptr[d + 1] - base;
  float p = 0.f;
  for (int i = l; i < cnt; i += 64) p += xs2[base + i];
#pragma unroll
  for (int o = 32; o; o >>= 1) p += __shfl_xor(p, o, 64);
  float rinv = 1.f / (p + 1e-16f);
  int e = l >> 5;
  int c2 = (l & 31) * 2;
  float2 acc = make_float2(0.f, 0.f);
  int i = 0;
  for (; i + 16 <= cnt; i += 16) {
    int s[8];
    float xv[8];
    __half2 v[8];
#pragma unroll
    for (int j = 0; j < 8; j++) {
      int idx = base + i + j * 2 + e;
      s[j] = csr_src[idx];
      xv[j] = xs2[idx];
    }
#pragma unroll
    for (int j = 0; j < 8; j++)
      v[j] = *(const __half2*)(h2h + (size_t)s[j] * 64 + c2);
#pragma unroll
    for (int j = 0; j < 8; j++) {
      float a = xv[j] * rinv;
      float2 f = __half22float2(v[j]);
      acc.x = fmaf(f.x, a, acc.x);
      acc.y = fmaf(f.y, a, acc.y);
    }
  }
  for (; i + e < cnt; i += 2) {
    int idx = base + i + e;
    int s = csr_src[idx];
    float a = xs2[idx] * rinv;
    float2 f = __half22float2(*(const __half2*)(h2h + (size_t)s * 64 + c2));
    acc.x = fmaf(f.x, a, acc.x);
    acc.y = fmaf(f.y, a, acc.y);
  }
  acc.x += __shfl_xor(acc.x, 32, 64);
  acc.y += __shfl_xor(acc.y, 32, 64);
  if (l < 32) {
    float2 b = *(const float2*)(bias + c2);
    *(float2*)(out + (size_t)d * 64 + c2) = make_float2(acc.x + b.x, acc.y + b.y);
  }
}

// ---------------------------------------------------------------------------
extern "C" void kernel_launch(void* const* d_in, const int* in_sizes, int n_in,
                              void* d_out, int out_size, void* d_ws, size_t ws_size,
                              hipStream_t stream) {
  const float* x        = (const float*)d_in[0];
  const int*   ei       = (const int*)d_in[1];
  const float* W1       = (const float*)d_in[3];
  const float* att_src1 = (const float*)d_in[4];
  const float* att_dst1 = (const float*)d_in[5];
  const float* bias1    = (const float*)d_in[6];
  const float* W2       = (const float*)d_in[7];
  const float* att_src2 = (const float*)d_in[8];
  const float* att_dst2 = (const float*)d_in[9];
  const float* bias2    = (const float*)d_in[10];
  float* out = (float*)d_out;

  int N = in_sizes[0] / 128;
  int E = in_sizes[1] / 2;
  int Etot = E + N;
  int nb = (N + 255) / 256;

  char* ws = (char*)d_ws;
  size_t off = 0;
  auto carve = [&](size_t bytes) -> void* {
    void* p = ws + off;
    off += (bytes + 255) & ~(size_t)255;
    return p;
  };
  __half* h1h   = (__half*)carve((size_t)N * 256 * 2);
  __half* h2h   = (__half*)carve((size_t)N * 64 * 2);
  float* h_act  = (float*)carve((size_t)N * 256 * 4);
  float* a_src1 = (float*)carve((size_t)N * 8 * 4);
  float* a_dst1 = (float*)carve((size_t)N * 8 * 4);
  float* a_src2 = (float*)carve((size_t)N * 4);
  float* a_dst2 = (float*)carve((size_t)N * 4);
  int* rowptr   = (int*)carve((size_t)(N + 1) * 4);
  int* cursor   = (int*)carve((size_t)N * 4);
  int* deg      = (int*)carve((size_t)N * 4);
  int* bsum     = (int*)carve((size_t)nb * 4);
  int* csr_src  = (int*)carve((size_t)Etot * 4);
  int* csr_dst  = (int*)carve((size_t)Etot * 4);
  float* xs1    = (float*)carve((size_t)Etot * 8 * 4);
  float* xs2    = (float*)carve((size_t)Etot * 4);
  (void)ws_size; (void)n_in; (void)out_size;

  // layer-1 projection (fp16 out) + attention coefficients
  {
    dim3 g((N + 127) / 128, 4);
    gemm_half_kernel<128, 256><<<g, 256, 0, stream>>>(x, W1, h1h, N);
  }
  att1_kernel<<<(N * 8 + 255) / 256, 256, 0, stream>>>(h1h, att_src1, att_dst1,
                                                       a_src1, a_dst1, N);
  // CSR build
  hipMemsetAsync(deg, 0, (size_t)N * 4, stream);
  hist_kernel<<<(Etot + 255) / 256, 256, 0, stream>>>(ei, E, N, deg);
  scan1_kernel<<<nb, 256, 0, stream>>>(deg, bsum, N);
  scan2_kernel<<<1, 1024, 0, stream>>>(bsum, nb);
  scan3_kernel<<<nb, 256, 0, stream>>>(deg, bsum, rowptr, cursor, N);
  scatter_kernel<<<(Etot + 255) / 256, 256, 0, stream>>>(ei, E, N, cursor,
                                                         csr_src, csr_dst);
  // layer-1 softmax numerators + aggregation (+bias+ELU)
  xs1_kernel<<<(Etot * 8 + 255) / 256, 256, 0, stream>>>(csr_src, csr_dst,
                                                         a_src1, a_dst1, xs1, Etot);
  agg1_kernel<<<(N + 3) / 4, 256, 0, stream>>>(rowptr, csr_src, xs1, h1h,
                                               bias1, h_act, N);
  // layer 2
  {
    dim3 g((N + 127) / 128, 1);
    gemm_half_kernel<256, 64><<<g, 256, 0, stream>>>(h_act, W2, h2h, N);
  }
  att2_kernel<<<(N + 255) / 256, 256, 0, stream>>>(h2h, att_src2, att_dst2,
                                                   a_src2, a_dst2, N);
  xs2_kernel<<<(Etot + 255) / 256, 256, 0, stream>>>(csr_src, csr_dst,
                                                     a_src2, a_dst2, xs2, Etot);
  agg2_kernel<<<(N + 3) / 4, 256, 0, stream>>>(rowptr, csr_src, xs2, h2h,
                                               bias2, out, N);
}